// Round 7
// baseline (345.906 us; speedup 1.0000x reference)
//
#include <hip/hip_runtime.h>

#define NN 4096
#define IN_DIM 512
#define HID 256
#define OUT_DIM 128
#define MAXDEG 192
#define INV_GAMMA (1.0f / 6.0f)
#define LAM 0.11111111111111116f   // 1/0.9 - 1
#define PROP_STEPS 10

// ---------------------------------------------------------------------------
// Dense A scan (float4): per-row adjacency list, degree, D=rowsum+1, 1/D, 1/sqrt(D).
__global__ void k_analyze(const float* __restrict__ A, unsigned short* __restrict__ cols,
                          int* __restrict__ deg, float* __restrict__ DsqInv,
                          float* __restrict__ Dinv) {
    int wid = threadIdx.x >> 6, lane = threadIdx.x & 63;
    int row = blockIdx.x * 4 + wid;
    const float4* Ar = (const float4*)(A + (size_t)row * NN);
    unsigned short* crow = cols + (size_t)row * MAXDEG;
    int cnt = 0;
    float fsum = 0.f;
    for (int it = 0; it < NN / 256; ++it) {
        float4 v = Ar[it * 64 + lane];
        fsum += (v.x + v.y) + (v.z + v.w);
        int colbase = (it * 64 + lane) * 4;
        float comp[4] = {v.x, v.y, v.z, v.w};
#pragma unroll
        for (int c = 0; c < 4; ++c) {
            bool nz = (comp[c] != 0.f);
            unsigned long long m = __ballot(nz);
            if (nz) {
                int off = cnt + __popcll(m & ((1ull << lane) - 1ull));
                if (off < MAXDEG) crow[off] = (unsigned short)(colbase + c);
            }
            cnt += __popcll(m);
        }
    }
#pragma unroll
    for (int m = 1; m < 64; m <<= 1) fsum += __shfl_xor(fsum, m);
    if (lane == 0) {
        float D = fsum + 1.0f;
        deg[row] = cnt < MAXDEG ? cnt : MAXDEG;
        DsqInv[row] = 1.0f / sqrtf(D);
        Dinv[row] = 1.0f / D;
    }
}

// ---------------------------------------------------------------------------
// Fused MLP: F0 = relu(F@W1+b1)@W2 + b2; X0 = F0/sqrt(D).
// 256 blocks x 16 rows, 256 threads.  R=4 rows/thread in layer 1 (4kk register
// groups: 8 b128 LDS reads per 64 FMA) + W-tile register prefetch.
// LDS: sF 32KB + sW 32KB + sHT 18KB = 82KB (1 block/CU; grid=256=1/CU).
__global__ __launch_bounds__(256) void k_mlp(const float* __restrict__ F,
                      const float* __restrict__ W1, const float* __restrict__ b1,
                      const float* __restrict__ W2, const float* __restrict__ b2,
                      const float* __restrict__ DsqInv,
                      float* __restrict__ F0, float* __restrict__ X0) {
    __shared__ __align__(16) float sF[16 * IN_DIM];    // [16][512] row-major, 32KB
    __shared__ __align__(16) float sW[32 * 256];       // W tile, 32KB
    __shared__ float sHT[HID * 18];                    // H transposed [256][18], 18KB
    int t = threadIdx.x;
    int r0 = blockIdx.x * 16;
    const float4* F4 = (const float4*)F;
    const float4* W1_4 = (const float4*)W1;
    const float4* W2_4 = (const float4*)W2;
    float4* sF4 = (float4*)sF;
    float4* sW4 = (float4*)sW;

    // stage 16 F rows: 2048 float4 / 256 thr = 8 each (coalesced)
#pragma unroll
    for (int i = 0; i < 8; ++i) {
        int idx = i * 256 + t;
        int r = idx >> 7, q = idx & 127;
        sF4[r * 128 + q] = F4[(size_t)(r0 + r) * 128 + q];
    }
    // prefetch W1 tile kt=0 into regs
    float4 wreg[8];
#pragma unroll
    for (int i = 0; i < 8; ++i) {
        int idx = i * 256 + t;
        int kr = idx >> 6, q = idx & 63;
        wreg[i] = W1_4[(size_t)kr * 64 + q];
    }
    {   // ---- layer 1: thread = (4 cols, 4 rows) ----
        int cq = t & 63, rg = t >> 6;
        float4 acc[4];
#pragma unroll
        for (int j = 0; j < 4; ++j) acc[j] = make_float4(0.f, 0.f, 0.f, 0.f);
        for (int kt = 0; kt < IN_DIM / 32; ++kt) {
            __syncthreads();
#pragma unroll
            for (int i = 0; i < 8; ++i) {       // regs -> LDS
                int idx = i * 256 + t;
                int kr = idx >> 6, q = idx & 63;
                sW4[kr * 64 + q] = wreg[i];
            }
            __syncthreads();
            if (kt < IN_DIM / 32 - 1) {         // prefetch next tile
#pragma unroll
                for (int i = 0; i < 8; ++i) {
                    int idx = i * 256 + t;
                    int kr = idx >> 6, q = idx & 63;
                    wreg[i] = W1_4[(size_t)((kt + 1) * 32 + kr) * 64 + q];
                }
            }
#pragma unroll
            for (int g4 = 0; g4 < 8; ++g4) {    // 4 kk per group
                float4 w0 = sW4[(4 * g4 + 0) * 64 + cq];
                float4 w1 = sW4[(4 * g4 + 1) * 64 + cq];
                float4 w2 = sW4[(4 * g4 + 2) * 64 + cq];
                float4 w3 = sW4[(4 * g4 + 3) * 64 + cq];
#pragma unroll
                for (int j = 0; j < 4; ++j) {
                    float4 f = sF4[(4 * rg + j) * 128 + kt * 8 + g4];
                    acc[j].x = fmaf(f.x, w0.x, acc[j].x); acc[j].y = fmaf(f.x, w0.y, acc[j].y);
                    acc[j].z = fmaf(f.x, w0.z, acc[j].z); acc[j].w = fmaf(f.x, w0.w, acc[j].w);
                    acc[j].x = fmaf(f.y, w1.x, acc[j].x); acc[j].y = fmaf(f.y, w1.y, acc[j].y);
                    acc[j].z = fmaf(f.y, w1.z, acc[j].z); acc[j].w = fmaf(f.y, w1.w, acc[j].w);
                    acc[j].x = fmaf(f.z, w2.x, acc[j].x); acc[j].y = fmaf(f.z, w2.y, acc[j].y);
                    acc[j].z = fmaf(f.z, w2.z, acc[j].z); acc[j].w = fmaf(f.z, w2.w, acc[j].w);
                    acc[j].x = fmaf(f.w, w3.x, acc[j].x); acc[j].y = fmaf(f.w, w3.y, acc[j].y);
                    acc[j].z = fmaf(f.w, w3.z, acc[j].z); acc[j].w = fmaf(f.w, w3.w, acc[j].w);
                }
            }
        }
        float4 b = *(const float4*)&b1[4 * cq];
#pragma unroll
        for (int j = 0; j < 4; ++j) {           // relu + transposed store to sHT
            float hx = fmaxf(acc[j].x + b.x, 0.f);
            float hy = fmaxf(acc[j].y + b.y, 0.f);
            float hz = fmaxf(acc[j].z + b.z, 0.f);
            float hw = fmaxf(acc[j].w + b.w, 0.f);
            int r = 4 * rg + j;
            sHT[(4 * cq + 0) * 18 + r] = hx;
            sHT[(4 * cq + 1) * 18 + r] = hy;
            sHT[(4 * cq + 2) * 18 + r] = hz;
            sHT[(4 * cq + 3) * 18 + r] = hw;
        }
    }
    // prefetch W2 tile kt=0
#pragma unroll
    for (int i = 0; i < 4; ++i) {
        int idx = i * 256 + t;
        int kr = idx >> 5, q = idx & 31;
        wreg[i] = W2_4[(size_t)kr * 32 + q];
    }
    {   // ---- layer 2: thread = (4 cols, 2 rows) ----
        int cq2 = t & 31, rg2 = t >> 5;         // rows 2*rg2, 2*rg2+1
        float4 accA = make_float4(0.f, 0.f, 0.f, 0.f);
        float4 accB = make_float4(0.f, 0.f, 0.f, 0.f);
        for (int kt = 0; kt < HID / 32; ++kt) {
            __syncthreads();
#pragma unroll
            for (int i = 0; i < 4; ++i) {
                int idx = i * 256 + t;
                int kr = idx >> 5, q = idx & 31;
                sW4[kr * 32 + q] = wreg[i];
            }
            __syncthreads();
            if (kt < HID / 32 - 1) {
#pragma unroll
                for (int i = 0; i < 4; ++i) {
                    int idx = i * 256 + t;
                    int kr = idx >> 5, q = idx & 31;
                    wreg[i] = W2_4[(size_t)((kt + 1) * 32 + kr) * 32 + q];
                }
            }
#pragma unroll
            for (int kk = 0; kk < 32; ++kk) {
                float4 w = sW4[kk * 32 + cq2];
                float2 f = *(const float2*)&sHT[(kt * 32 + kk) * 18 + 2 * rg2];
                accA.x = fmaf(f.x, w.x, accA.x); accA.y = fmaf(f.x, w.y, accA.y);
                accA.z = fmaf(f.x, w.z, accA.z); accA.w = fmaf(f.x, w.w, accA.w);
                accB.x = fmaf(f.y, w.x, accB.x); accB.y = fmaf(f.y, w.y, accB.y);
                accB.z = fmaf(f.y, w.z, accB.z); accB.w = fmaf(f.y, w.w, accB.w);
            }
        }
        float4 b = *(const float4*)&b2[4 * cq2];
        int rowA = r0 + 2 * rg2, rowB = rowA + 1;
        float dsA = DsqInv[rowA], dsB = DsqInv[rowB];
        float4 oA, oB, xA, xB;
        oA.x = accA.x + b.x; oA.y = accA.y + b.y; oA.z = accA.z + b.z; oA.w = accA.w + b.w;
        oB.x = accB.x + b.x; oB.y = accB.y + b.y; oB.z = accB.z + b.z; oB.w = accB.w + b.w;
        xA.x = oA.x * dsA; xA.y = oA.y * dsA; xA.z = oA.z * dsA; xA.w = oA.w * dsA;
        xB.x = oB.x * dsB; xB.y = oB.y * dsB; xB.z = oB.z * dsB; xB.w = oB.w * dsB;
        ((float4*)F0)[(size_t)rowA * 32 + cq2] = oA;
        ((float4*)F0)[(size_t)rowB * 32 + cq2] = oB;
        ((float4*)X0)[(size_t)rowA * 32 + cq2] = xA;
        ((float4*)X0)[(size_t)rowB * 32 + cq2] = xB;
    }
}

// ---------------------------------------------------------------------------
// Fused IRLS step v3: wave per row, 16-lane group per edge (4 edges in flight),
// 2-deep ping-pong prefetch of X_j.  Low VGPR -> better latency hiding.
__global__ __launch_bounds__(256, 4) void k_prop(const float* __restrict__ X,
                       const float* __restrict__ F0,
                       const unsigned short* __restrict__ cols, const int* __restrict__ deg,
                       const float* __restrict__ DsqInv, const float* __restrict__ Dinv,
                       float* __restrict__ Xout, float* __restrict__ FcOut, int final_step) {
    __shared__ unsigned short sCols[4][MAXDEG];
    int wid = threadIdx.x >> 6, lane = threadIdx.x & 63;
    int row = blockIdx.x * 4 + wid;
    int g = lane >> 4, oc = lane & 15;         // 4 groups x 16 lanes
    int dg = deg[row];
    float dsi = DsqInv[row], di = Dinv[row];
    for (int e = lane; e < dg; e += 64) sCols[wid][e] = cols[(size_t)row * MAXDEG + e];

    const float4* Xr = (const float4*)(X + (size_t)row * 128);
    float4 xiA = Xr[oc], xiB = Xr[16 + oc];    // components 4oc..4oc+3, 64+4oc..
    float sqi;
    {
        float s = 0.f;
        s = fmaf(xiA.x, xiA.x, s); s = fmaf(xiA.y, xiA.y, s);
        s = fmaf(xiA.z, xiA.z, s); s = fmaf(xiA.w, xiA.w, s);
        s = fmaf(xiB.x, xiB.x, s); s = fmaf(xiB.y, xiB.y, s);
        s = fmaf(xiB.z, xiB.z, s); s = fmaf(xiB.w, xiB.w, s);
        s += __shfl_xor(s, 1); s += __shfl_xor(s, 2);
        s += __shfl_xor(s, 4); s += __shfl_xor(s, 8);
        sqi = s;
    }
    float4 accA = make_float4(0.f, 0.f, 0.f, 0.f);
    float4 accB = make_float4(0.f, 0.f, 0.f, 0.f);
    float qacc = 0.f;
    if (dg > 0) {
        int nch = (dg + 3) >> 2;
        int e0 = (g < dg) ? g : (dg - 1);
        int j0 = (int)sCols[wid][e0];
        const float4* Xj = (const float4*)(X + (size_t)j0 * 128);
        float4 cA = Xj[oc], cB = Xj[16 + oc];
        for (int ch = 0; ch < nch; ++ch) {
            // prefetch next chunk (clamped; last iter loads a harmless dup)
            int en = (ch + 1) * 4 + g; en = (en < dg) ? en : (dg - 1);
            int jn = (int)sCols[wid][en];
            const float4* Xn = (const float4*)(X + (size_t)jn * 128);
            float4 nA = Xn[oc], nB = Xn[16 + oc];
            // compute with current chunk
            float p = 0.f, sj = 0.f;
            p = fmaf(xiA.x, cA.x, p); sj = fmaf(cA.x, cA.x, sj);
            p = fmaf(xiA.y, cA.y, p); sj = fmaf(cA.y, cA.y, sj);
            p = fmaf(xiA.z, cA.z, p); sj = fmaf(cA.z, cA.z, sj);
            p = fmaf(xiA.w, cA.w, p); sj = fmaf(cA.w, cA.w, sj);
            p = fmaf(xiB.x, cB.x, p); sj = fmaf(cB.x, cB.x, sj);
            p = fmaf(xiB.y, cB.y, p); sj = fmaf(cB.y, cB.y, sj);
            p = fmaf(xiB.z, cB.z, p); sj = fmaf(cB.z, cB.z, sj);
            p = fmaf(xiB.w, cB.w, p); sj = fmaf(cB.w, cB.w, sj);
            p += __shfl_xor(p, 1); sj += __shfl_xor(sj, 1);
            p += __shfl_xor(p, 2); sj += __shfl_xor(sj, 2);
            p += __shfl_xor(p, 4); sj += __shfl_xor(sj, 4);
            p += __shfl_xor(p, 8); sj += __shfl_xor(sj, 8);
            float z = fmaxf(sqi + sj - 2.f * p, 0.f);
            float w = fmaxf(1.f - sqrtf(z) * INV_GAMMA, 0.f);
            bool act = (ch * 4 + g) < dg;
            w = act ? w : 0.f;
            qacc += w;
            accA.x = fmaf(w, cA.x, accA.x); accA.y = fmaf(w, cA.y, accA.y);
            accA.z = fmaf(w, cA.z, accA.z); accA.w = fmaf(w, cA.w, accA.w);
            accB.x = fmaf(w, cB.x, accB.x); accB.y = fmaf(w, cB.y, accB.y);
            accB.z = fmaf(w, cB.z, accB.z); accB.w = fmaf(w, cB.w, accB.w);
            cA = nA; cB = nB;
        }
    }
    // reduce across the 4 groups (lane bits 4,5)
#pragma unroll
    for (int m = 16; m <= 32; m <<= 1) {
        qacc += __shfl_xor(qacc, m);
        accA.x += __shfl_xor(accA.x, m); accA.y += __shfl_xor(accA.y, m);
        accA.z += __shfl_xor(accA.z, m); accA.w += __shfl_xor(accA.w, m);
        accB.x += __shfl_xor(accB.x, m); accB.y += __shfl_xor(accB.y, m);
        accB.z += __shfl_xor(accB.z, m); accB.w += __shfl_xor(accB.w, m);
    }
    float invQ = 1.f / (qacc * di + LAM);
    if (g == 0) {   // lanes 0..15 write the 128-dim row
        const float4* F04 = (const float4*)(F0 + (size_t)row * 128);
        float4 f0A = F04[oc], f0B = F04[16 + oc];
        float4 oA, oB;
        oA.x = (dsi * accA.x + LAM * f0A.x) * invQ;
        oA.y = (dsi * accA.y + LAM * f0A.y) * invQ;
        oA.z = (dsi * accA.z + LAM * f0A.z) * invQ;
        oA.w = (dsi * accA.w + LAM * f0A.w) * invQ;
        oB.x = (dsi * accB.x + LAM * f0B.x) * invQ;
        oB.y = (dsi * accB.y + LAM * f0B.y) * invQ;
        oB.z = (dsi * accB.z + LAM * f0B.z) * invQ;
        oB.w = (dsi * accB.w + LAM * f0B.w) * invQ;
        if (final_step) {
            float4* dst = (float4*)(FcOut + (size_t)row * 128);
            dst[oc] = oA; dst[16 + oc] = oB;
        } else {
            float4 xA, xB;
            xA.x = oA.x * dsi; xA.y = oA.y * dsi; xA.z = oA.z * dsi; xA.w = oA.w * dsi;
            xB.x = oB.x * dsi; xB.y = oB.y * dsi; xB.z = oB.z * dsi; xB.w = oB.w * dsi;
            float4* dst = (float4*)(Xout + (size_t)row * 128);
            dst[oc] = xA; dst[16 + oc] = xB;
        }
    }
}

extern "C" void kernel_launch(void* const* d_in, const int* in_sizes, int n_in,
                              void* d_out, int out_size, void* d_ws, size_t ws_size,
                              hipStream_t stream) {
    const float *A = nullptr, *F = nullptr, *W1 = nullptr, *b1 = nullptr,
                *W2 = nullptr, *b2 = nullptr;
    for (int i = 0; i < n_in; i++) {
        switch (in_sizes[i]) {
            case NN * NN:        A  = (const float*)d_in[i]; break;
            case NN * IN_DIM:    F  = (const float*)d_in[i]; break;
            case IN_DIM * HID:   W1 = (const float*)d_in[i]; break;
            case HID:            b1 = (const float*)d_in[i]; break;
            case HID * OUT_DIM:  W2 = (const float*)d_in[i]; break;
            case OUT_DIM:        b2 = (const float*)d_in[i]; break;
            default: break;
        }
    }
    float* out = (float*)d_out;

    char* ws = (char*)d_ws;
    float* F0     = (float*)ws; ws += (size_t)NN * OUT_DIM * 4;   // 2 MB
    float* XA     = (float*)ws; ws += (size_t)NN * OUT_DIM * 4;   // 2 MB
    float* XB     = (float*)ws; ws += (size_t)NN * OUT_DIM * 4;   // 2 MB
    float* DsqInv = (float*)ws; ws += (size_t)NN * 4;
    float* Dinv   = (float*)ws; ws += (size_t)NN * 4;
    int*   deg    = (int*)ws;   ws += (size_t)NN * 4;
    unsigned short* cols = (unsigned short*)ws; ws += (size_t)NN * MAXDEG * 2; // 1.5 MB

    hipLaunchKernelGGL(k_analyze, dim3(NN / 4), dim3(256), 0, stream, A, cols, deg, DsqInv, Dinv);
    hipLaunchKernelGGL(k_mlp, dim3(NN / 16), dim3(256), 0, stream,
                       F, W1, b1, W2, b2, DsqInv, F0, XA);

    float* Xc = XA; float* Xn = XB;
    for (int step = 0; step < PROP_STEPS; step++) {
        int fin = (step == PROP_STEPS - 1) ? 1 : 0;
        hipLaunchKernelGGL(k_prop, dim3(NN / 4), dim3(256), 0, stream,
                           Xc, F0, cols, deg, DsqInv, Dinv, Xn, out, fin);
        float* t1 = Xc; Xc = Xn; Xn = t1;
    }
}

// Round 8
// 318.781 us; speedup vs baseline: 1.0851x; 1.0851x over previous
//
#include <hip/hip_runtime.h>

#define NN 4096
#define IN_DIM 512
#define HID 256
#define OUT_DIM 128
#define MAXDEG 192
#define INV_GAMMA (1.0f / 6.0f)
#define LAM 0.11111111111111116f   // 1/0.9 - 1
#define PROP_STEPS 10

// ---------------------------------------------------------------------------
// Dense A scan (float4): per-row adjacency list, degree, D=rowsum+1, 1/D, 1/sqrt(D).
__global__ void k_analyze(const float* __restrict__ A, unsigned short* __restrict__ cols,
                          int* __restrict__ deg, float* __restrict__ DsqInv,
                          float* __restrict__ Dinv) {
    int wid = threadIdx.x >> 6, lane = threadIdx.x & 63;
    int row = blockIdx.x * 4 + wid;
    const float4* Ar = (const float4*)(A + (size_t)row * NN);
    unsigned short* crow = cols + (size_t)row * MAXDEG;
    int cnt = 0;
    float fsum = 0.f;
    for (int it = 0; it < NN / 256; ++it) {
        float4 v = Ar[it * 64 + lane];
        fsum += (v.x + v.y) + (v.z + v.w);
        int colbase = (it * 64 + lane) * 4;
        float comp[4] = {v.x, v.y, v.z, v.w};
#pragma unroll
        for (int c = 0; c < 4; ++c) {
            bool nz = (comp[c] != 0.f);
            unsigned long long m = __ballot(nz);
            if (nz) {
                int off = cnt + __popcll(m & ((1ull << lane) - 1ull));
                if (off < MAXDEG) crow[off] = (unsigned short)(colbase + c);
            }
            cnt += __popcll(m);
        }
    }
#pragma unroll
    for (int m = 1; m < 64; m <<= 1) fsum += __shfl_xor(fsum, m);
    if (lane == 0) {
        float D = fsum + 1.0f;
        deg[row] = cnt < MAXDEG ? cnt : MAXDEG;
        DsqInv[row] = 1.0f / sqrtf(D);
        Dinv[row] = 1.0f / D;
    }
}

// ---------------------------------------------------------------------------
// Fused MLP (round-6 shell + float4 f-reads in layer 1).
// 512 blocks x 8 rows, 256 threads, 56KB LDS -> 2 blocks/CU.
__global__ __launch_bounds__(256) void k_mlp(const float* __restrict__ F,
                      const float* __restrict__ W1, const float* __restrict__ b1,
                      const float* __restrict__ W2, const float* __restrict__ b2,
                      const float* __restrict__ DsqInv,
                      float* __restrict__ F0, float* __restrict__ X0) {
    __shared__ __align__(16) float sF[8 * IN_DIM];   // 16 KB
    __shared__ __align__(16) float sW[32 * 256];     // 32 KB
    __shared__ __align__(16) float sH[8 * HID];      // 8 KB
    int r0 = blockIdx.x * 8;
    int t = threadIdx.x;
    float4* sF4 = (float4*)sF;
    float4* sW4 = (float4*)sW;
#pragma unroll
    for (int i = 0; i < 4; ++i) {
        int idx = i * 256 + t;
        int r = idx >> 7, q = idx & 127;
        sF4[r * 128 + q] = *(const float4*)&F[(size_t)(r0 + r) * IN_DIM + 4 * q];
    }
    {   // layer 1: thread = (4 cols, 2 rows); per g4 (4 kk): 4 w-b128 + 2 f-b128
        int cq = t & 63, rg = t >> 6;
        float4 accA = make_float4(0.f, 0.f, 0.f, 0.f);
        float4 accB = make_float4(0.f, 0.f, 0.f, 0.f);
        for (int kt = 0; kt < IN_DIM / 32; ++kt) {
            __syncthreads();
#pragma unroll
            for (int i = 0; i < 8; ++i) {     // stage W1 tile [32][256]
                int idx = i * 256 + t;
                int kr = idx >> 6, q = idx & 63;
                sW4[kr * 64 + q] = *(const float4*)&W1[(size_t)(kt * 32 + kr) * HID + 4 * q];
            }
            __syncthreads();
#pragma unroll
            for (int g4 = 0; g4 < 8; ++g4) {
                float4 w0 = sW4[(4 * g4 + 0) * 64 + cq];
                float4 w1 = sW4[(4 * g4 + 1) * 64 + cq];
                float4 w2 = sW4[(4 * g4 + 2) * 64 + cq];
                float4 w3 = sW4[(4 * g4 + 3) * 64 + cq];
                float4 fA = sF4[(2 * rg) * 128 + kt * 8 + g4];
                float4 fB = sF4[(2 * rg + 1) * 128 + kt * 8 + g4];
                accA.x = fmaf(fA.x, w0.x, accA.x); accA.y = fmaf(fA.x, w0.y, accA.y);
                accA.z = fmaf(fA.x, w0.z, accA.z); accA.w = fmaf(fA.x, w0.w, accA.w);
                accA.x = fmaf(fA.y, w1.x, accA.x); accA.y = fmaf(fA.y, w1.y, accA.y);
                accA.z = fmaf(fA.y, w1.z, accA.z); accA.w = fmaf(fA.y, w1.w, accA.w);
                accA.x = fmaf(fA.z, w2.x, accA.x); accA.y = fmaf(fA.z, w2.y, accA.y);
                accA.z = fmaf(fA.z, w2.z, accA.z); accA.w = fmaf(fA.z, w2.w, accA.w);
                accA.x = fmaf(fA.w, w3.x, accA.x); accA.y = fmaf(fA.w, w3.y, accA.y);
                accA.z = fmaf(fA.w, w3.z, accA.z); accA.w = fmaf(fA.w, w3.w, accA.w);
                accB.x = fmaf(fB.x, w0.x, accB.x); accB.y = fmaf(fB.x, w0.y, accB.y);
                accB.z = fmaf(fB.x, w0.z, accB.z); accB.w = fmaf(fB.x, w0.w, accB.w);
                accB.x = fmaf(fB.y, w1.x, accB.x); accB.y = fmaf(fB.y, w1.y, accB.y);
                accB.z = fmaf(fB.y, w1.z, accB.z); accB.w = fmaf(fB.y, w1.w, accB.w);
                accB.x = fmaf(fB.z, w2.x, accB.x); accB.y = fmaf(fB.z, w2.y, accB.y);
                accB.z = fmaf(fB.z, w2.z, accB.z); accB.w = fmaf(fB.z, w2.w, accB.w);
                accB.x = fmaf(fB.w, w3.x, accB.x); accB.y = fmaf(fB.w, w3.y, accB.y);
                accB.z = fmaf(fB.w, w3.z, accB.z); accB.w = fmaf(fB.w, w3.w, accB.w);
            }
        }
        float4 b = *(const float4*)&b1[4 * cq];
        float4 ha, hb;
        ha.x = fmaxf(accA.x + b.x, 0.f); ha.y = fmaxf(accA.y + b.y, 0.f);
        ha.z = fmaxf(accA.z + b.z, 0.f); ha.w = fmaxf(accA.w + b.w, 0.f);
        hb.x = fmaxf(accB.x + b.x, 0.f); hb.y = fmaxf(accB.y + b.y, 0.f);
        hb.z = fmaxf(accB.z + b.z, 0.f); hb.w = fmaxf(accB.w + b.w, 0.f);
        *(float4*)&sH[(2 * rg) * HID + 4 * cq] = ha;
        *(float4*)&sH[(2 * rg + 1) * HID + 4 * cq] = hb;
    }
    {   // layer 2 (round-6 pattern): thread = (1 col, 4 rows)
        int c = t & 127, half = t >> 7;
        float acc2[4] = {0.f, 0.f, 0.f, 0.f};
        for (int kt = 0; kt < HID / 32; ++kt) {
            __syncthreads();
#pragma unroll
            for (int i = 0; i < 4; ++i) {     // stage W2 tile [32][128]
                int idx = i * 256 + t;
                int kr = idx >> 5, q = idx & 31;
                sW4[kr * 32 + q] = *(const float4*)&W2[(size_t)(kt * 32 + kr) * OUT_DIM + 4 * q];
            }
            __syncthreads();
#pragma unroll
            for (int kk = 0; kk < 32; ++kk) {
                int k = kt * 32 + kk;
                float w = sW[kk * 128 + c];
#pragma unroll
                for (int r = 0; r < 4; ++r)
                    acc2[r] = fmaf(sH[(half * 4 + r) * HID + k], w, acc2[r]);
            }
        }
        float b = b2[c];
#pragma unroll
        for (int r = 0; r < 4; ++r) {
            int row = r0 + half * 4 + r;
            float v = acc2[r] + b;
            F0[(size_t)row * OUT_DIM + c] = v;
            X0[(size_t)row * OUT_DIM + c] = v * DsqInv[row];
        }
    }
}

// ---------------------------------------------------------------------------
// sq[i] = ||X_i||^2  (one wave per row)
__global__ void k_sq0(const float* __restrict__ X, float* __restrict__ sq) {
    int wid = threadIdx.x >> 6, lane = threadIdx.x & 63;
    int row = blockIdx.x * 4 + wid;
    float2 x = ((const float2*)X)[row * 64 + lane];
    float s = x.x * x.x + x.y * x.y;
#pragma unroll
    for (int m = 1; m < 64; m <<= 1) s += __shfl_xor(s, m);
    if (lane == 0) sq[row] = s;
}

// ---------------------------------------------------------------------------
// IRLS step v4: 2 waves per row (block = 2 rows), 8-lane group per edge,
// precomputed sq (no in-register ||X_j||^2), LDS partial-sum combine
// (no 51-shuffle cross-group reduce).  Low VGPR -> 6 waves/SIMD.
__global__ __launch_bounds__(256, 6) void k_prop(const float* __restrict__ X,
                       const float* __restrict__ F0,
                       const unsigned short* __restrict__ cols, const int* __restrict__ deg,
                       const float* __restrict__ DsqInv, const float* __restrict__ Dinv,
                       const float* __restrict__ sq_in,
                       float* __restrict__ Xout, float* __restrict__ sq_out,
                       float* __restrict__ FcOut, int final_step) {
    __shared__ unsigned short sCols[2][MAXDEG];
    __shared__ float sPart[2][16][130];     // [row][slot][128 dims + qacc@128]
    __shared__ float sQw[2][2];
    int t = threadIdx.x;
    int wave = t >> 6, lane = t & 63;
    int rl = wave >> 1, half = wave & 1;
    int row = blockIdx.x * 2 + rl;
    int g = lane >> 3, oc = lane & 7;
    int dg = deg[row];
    {   // stage cols (the row's 128 threads cooperate)
        int idx = half * 64 + lane;
        for (int e = idx; e < dg; e += 128)
            sCols[rl][e] = cols[(size_t)row * MAXDEG + e];
    }
    float sqi = sq_in[row];
    const float4* Xi4 = (const float4*)(X + (size_t)row * 128 + oc * 16);
    float4 xi0 = Xi4[0], xi1 = Xi4[1], xi2 = Xi4[2], xi3 = Xi4[3];
    __syncthreads();
    float4 a0 = make_float4(0.f,0.f,0.f,0.f), a1 = make_float4(0.f,0.f,0.f,0.f);
    float4 a2 = make_float4(0.f,0.f,0.f,0.f), a3 = make_float4(0.f,0.f,0.f,0.f);
    float qacc = 0.f;
    int nch = (dg + 15) >> 4;
    for (int ch = 0; ch < nch; ++ch) {
        int e = ch * 16 + half * 8 + g;
        bool act = e < dg;
        int j = (int)sCols[rl][act ? e : 0];
        const float4* Xj4 = (const float4*)(X + (size_t)j * 128 + oc * 16);
        float4 c0 = Xj4[0], c1 = Xj4[1], c2 = Xj4[2], c3 = Xj4[3];
        float sqj = sq_in[j];
        float pA = 0.f, pB = 0.f;
        pA = fmaf(xi0.x, c0.x, pA); pB = fmaf(xi0.y, c0.y, pB);
        pA = fmaf(xi0.z, c0.z, pA); pB = fmaf(xi0.w, c0.w, pB);
        pA = fmaf(xi1.x, c1.x, pA); pB = fmaf(xi1.y, c1.y, pB);
        pA = fmaf(xi1.z, c1.z, pA); pB = fmaf(xi1.w, c1.w, pB);
        pA = fmaf(xi2.x, c2.x, pA); pB = fmaf(xi2.y, c2.y, pB);
        pA = fmaf(xi2.z, c2.z, pA); pB = fmaf(xi2.w, c2.w, pB);
        pA = fmaf(xi3.x, c3.x, pA); pB = fmaf(xi3.y, c3.y, pB);
        pA = fmaf(xi3.z, c3.z, pA); pB = fmaf(xi3.w, c3.w, pB);
        float p = pA + pB;
        p += __shfl_xor(p, 1);
        p += __shfl_xor(p, 2);
        p += __shfl_xor(p, 4);
        float z = fmaxf(sqi + sqj - 2.f * p, 0.f);
        float w = fmaxf(1.f - sqrtf(z) * INV_GAMMA, 0.f);
        w = act ? w : 0.f;
        qacc += w;
        a0.x = fmaf(w, c0.x, a0.x); a0.y = fmaf(w, c0.y, a0.y);
        a0.z = fmaf(w, c0.z, a0.z); a0.w = fmaf(w, c0.w, a0.w);
        a1.x = fmaf(w, c1.x, a1.x); a1.y = fmaf(w, c1.y, a1.y);
        a1.z = fmaf(w, c1.z, a1.z); a1.w = fmaf(w, c1.w, a1.w);
        a2.x = fmaf(w, c2.x, a2.x); a2.y = fmaf(w, c2.y, a2.y);
        a2.z = fmaf(w, c2.z, a2.z); a2.w = fmaf(w, c2.w, a2.w);
        a3.x = fmaf(w, c3.x, a3.x); a3.y = fmaf(w, c3.y, a3.y);
        a3.z = fmaf(w, c3.z, a3.z); a3.w = fmaf(w, c3.w, a3.w);
    }
    int slot = half * 8 + g;
    *(float4*)&sPart[rl][slot][oc * 16 + 0]  = a0;
    *(float4*)&sPart[rl][slot][oc * 16 + 4]  = a1;
    *(float4*)&sPart[rl][slot][oc * 16 + 8]  = a2;
    *(float4*)&sPart[rl][slot][oc * 16 + 12] = a3;
    if (oc == 0) sPart[rl][slot][128] = qacc;
    __syncthreads();
    // combine: thread (rl2, d) sums 16 partials (conflict-free strided reads)
    int rl2 = t >> 7, d = t & 127;
    int row2 = blockIdx.x * 2 + rl2;
    float acc = 0.f, qs = 0.f;
#pragma unroll
    for (int s = 0; s < 16; ++s) {
        acc += sPart[rl2][s][d];
        qs  += sPart[rl2][s][128];      // broadcast read
    }
    float dsi = DsqInv[row2];
    float invQ = 1.f / (qs * Dinv[row2] + LAM);
    float o = (dsi * acc + LAM * F0[(size_t)row2 * 128 + d]) * invQ;
    if (final_step) {
        FcOut[(size_t)row2 * 128 + d] = o;
    } else {
        float x = o * dsi;
        Xout[(size_t)row2 * 128 + d] = x;
        float ss = x * x;
#pragma unroll
        for (int m = 1; m < 64; m <<= 1) ss += __shfl_xor(ss, m);
        if (lane == 0) sQw[rl2][wave & 1] = ss;
    }
    __syncthreads();
    if (!final_step && t < 2) sq_out[blockIdx.x * 2 + t] = sQw[t][0] + sQw[t][1];
}

extern "C" void kernel_launch(void* const* d_in, const int* in_sizes, int n_in,
                              void* d_out, int out_size, void* d_ws, size_t ws_size,
                              hipStream_t stream) {
    const float *A = nullptr, *F = nullptr, *W1 = nullptr, *b1 = nullptr,
                *W2 = nullptr, *b2 = nullptr;
    for (int i = 0; i < n_in; i++) {
        switch (in_sizes[i]) {
            case NN * NN:        A  = (const float*)d_in[i]; break;
            case NN * IN_DIM:    F  = (const float*)d_in[i]; break;
            case IN_DIM * HID:   W1 = (const float*)d_in[i]; break;
            case HID:            b1 = (const float*)d_in[i]; break;
            case HID * OUT_DIM:  W2 = (const float*)d_in[i]; break;
            case OUT_DIM:        b2 = (const float*)d_in[i]; break;
            default: break;
        }
    }
    float* out = (float*)d_out;

    char* ws = (char*)d_ws;
    float* F0     = (float*)ws; ws += (size_t)NN * OUT_DIM * 4;   // 2 MB
    float* XA     = (float*)ws; ws += (size_t)NN * OUT_DIM * 4;   // 2 MB
    float* XB     = (float*)ws; ws += (size_t)NN * OUT_DIM * 4;   // 2 MB
    float* DsqInv = (float*)ws; ws += (size_t)NN * 4;
    float* Dinv   = (float*)ws; ws += (size_t)NN * 4;
    float* sqA    = (float*)ws; ws += (size_t)NN * 4;
    float* sqB    = (float*)ws; ws += (size_t)NN * 4;
    int*   deg    = (int*)ws;   ws += (size_t)NN * 4;
    unsigned short* cols = (unsigned short*)ws; ws += (size_t)NN * MAXDEG * 2; // 1.5 MB

    hipLaunchKernelGGL(k_analyze, dim3(NN / 4), dim3(256), 0, stream, A, cols, deg, DsqInv, Dinv);
    hipLaunchKernelGGL(k_mlp, dim3(NN / 8), dim3(256), 0, stream,
                       F, W1, b1, W2, b2, DsqInv, F0, XA);
    hipLaunchKernelGGL(k_sq0, dim3(NN / 4), dim3(256), 0, stream, XA, sqA);

    float* Xc = XA; float* Xn = XB;
    float* sqc = sqA; float* sqn = sqB;
    for (int step = 0; step < PROP_STEPS; step++) {
        int fin = (step == PROP_STEPS - 1) ? 1 : 0;
        hipLaunchKernelGGL(k_prop, dim3(NN / 2), dim3(256), 0, stream,
                           Xc, F0, cols, deg, DsqInv, Dinv, sqc, Xn, sqn, out, fin);
        float* t1 = Xc; Xc = Xn; Xn = t1;
        float* t2 = sqc; sqc = sqn; sqn = t2;
    }
}

// Round 10
// 263.958 us; speedup vs baseline: 1.3105x; 1.2077x over previous
//
#include <hip/hip_runtime.h>

#define NN 4096
#define IN_DIM 512
#define HID 256
#define OUT_DIM 128
#define MAXDEG 192
#define INV_GAMMA (1.0f / 6.0f)
#define LAM 0.11111111111111116f   // 1/0.9 - 1
#define PROP_STEPS 10

// ---------------------------------------------------------------------------
// Dense A scan (float4): per-row adjacency list, degree, D=rowsum+1, 1/D, 1/sqrt(D).
__global__ void k_analyze(const float* __restrict__ A, unsigned short* __restrict__ cols,
                          int* __restrict__ deg, float* __restrict__ DsqInv,
                          float* __restrict__ Dinv) {
    int wid = threadIdx.x >> 6, lane = threadIdx.x & 63;
    int row = blockIdx.x * 4 + wid;
    const float4* Ar = (const float4*)(A + (size_t)row * NN);
    unsigned short* crow = cols + (size_t)row * MAXDEG;
    int cnt = 0;
    float fsum = 0.f;
    for (int it = 0; it < NN / 256; ++it) {
        float4 v = Ar[it * 64 + lane];
        fsum += (v.x + v.y) + (v.z + v.w);
        int colbase = (it * 64 + lane) * 4;
        float comp[4] = {v.x, v.y, v.z, v.w};
#pragma unroll
        for (int c = 0; c < 4; ++c) {
            bool nz = (comp[c] != 0.f);
            unsigned long long m = __ballot(nz);
            if (nz) {
                int off = cnt + __popcll(m & ((1ull << lane) - 1ull));
                if (off < MAXDEG) crow[off] = (unsigned short)(colbase + c);
            }
            cnt += __popcll(m);
        }
    }
#pragma unroll
    for (int m = 1; m < 64; m <<= 1) fsum += __shfl_xor(fsum, m);
    if (lane == 0) {
        float D = fsum + 1.0f;
        deg[row] = cnt < MAXDEG ? cnt : MAXDEG;
        DsqInv[row] = 1.0f / sqrtf(D);
        Dinv[row] = 1.0f / D;
    }
}

// ---------------------------------------------------------------------------
// Fused MLP (unchanged from round 8: 44 us, LDS-throughput-bound, understood).
__global__ __launch_bounds__(256) void k_mlp(const float* __restrict__ F,
                      const float* __restrict__ W1, const float* __restrict__ b1,
                      const float* __restrict__ W2, const float* __restrict__ b2,
                      const float* __restrict__ DsqInv,
                      float* __restrict__ F0, float* __restrict__ X0) {
    __shared__ __align__(16) float sF[8 * IN_DIM];   // 16 KB
    __shared__ __align__(16) float sW[32 * 256];     // 32 KB
    __shared__ __align__(16) float sH[8 * HID];      // 8 KB
    int r0 = blockIdx.x * 8;
    int t = threadIdx.x;
    float4* sF4 = (float4*)sF;
    float4* sW4 = (float4*)sW;
#pragma unroll
    for (int i = 0; i < 4; ++i) {
        int idx = i * 256 + t;
        int r = idx >> 7, q = idx & 127;
        sF4[r * 128 + q] = *(const float4*)&F[(size_t)(r0 + r) * IN_DIM + 4 * q];
    }
    {   // layer 1: thread = (4 cols, 2 rows)
        int cq = t & 63, rg = t >> 6;
        float4 accA = make_float4(0.f, 0.f, 0.f, 0.f);
        float4 accB = make_float4(0.f, 0.f, 0.f, 0.f);
        for (int kt = 0; kt < IN_DIM / 32; ++kt) {
            __syncthreads();
#pragma unroll
            for (int i = 0; i < 8; ++i) {     // stage W1 tile [32][256]
                int idx = i * 256 + t;
                int kr = idx >> 6, q = idx & 63;
                sW4[kr * 64 + q] = *(const float4*)&W1[(size_t)(kt * 32 + kr) * HID + 4 * q];
            }
            __syncthreads();
#pragma unroll
            for (int g4 = 0; g4 < 8; ++g4) {
                float4 w0 = sW4[(4 * g4 + 0) * 64 + cq];
                float4 w1 = sW4[(4 * g4 + 1) * 64 + cq];
                float4 w2 = sW4[(4 * g4 + 2) * 64 + cq];
                float4 w3 = sW4[(4 * g4 + 3) * 64 + cq];
                float4 fA = sF4[(2 * rg) * 128 + kt * 8 + g4];
                float4 fB = sF4[(2 * rg + 1) * 128 + kt * 8 + g4];
                accA.x = fmaf(fA.x, w0.x, accA.x); accA.y = fmaf(fA.x, w0.y, accA.y);
                accA.z = fmaf(fA.x, w0.z, accA.z); accA.w = fmaf(fA.x, w0.w, accA.w);
                accA.x = fmaf(fA.y, w1.x, accA.x); accA.y = fmaf(fA.y, w1.y, accA.y);
                accA.z = fmaf(fA.y, w1.z, accA.z); accA.w = fmaf(fA.y, w1.w, accA.w);
                accA.x = fmaf(fA.z, w2.x, accA.x); accA.y = fmaf(fA.z, w2.y, accA.y);
                accA.z = fmaf(fA.z, w2.z, accA.z); accA.w = fmaf(fA.z, w2.w, accA.w);
                accA.x = fmaf(fA.w, w3.x, accA.x); accA.y = fmaf(fA.w, w3.y, accA.y);
                accA.z = fmaf(fA.w, w3.z, accA.z); accA.w = fmaf(fA.w, w3.w, accA.w);
                accB.x = fmaf(fB.x, w0.x, accB.x); accB.y = fmaf(fB.x, w0.y, accB.y);
                accB.z = fmaf(fB.x, w0.z, accB.z); accB.w = fmaf(fB.x, w0.w, accB.w);
                accB.x = fmaf(fB.y, w1.x, accB.x); accB.y = fmaf(fB.y, w1.y, accB.y);
                accB.z = fmaf(fB.y, w1.z, accB.z); accB.w = fmaf(fB.y, w1.w, accB.w);
                accB.x = fmaf(fB.z, w2.x, accB.x); accB.y = fmaf(fB.z, w2.y, accB.y);
                accB.z = fmaf(fB.z, w2.z, accB.z); accB.w = fmaf(fB.z, w2.w, accB.w);
                accB.x = fmaf(fB.w, w3.x, accB.x); accB.y = fmaf(fB.w, w3.y, accB.y);
                accB.z = fmaf(fB.w, w3.z, accB.z); accB.w = fmaf(fB.w, w3.w, accB.w);
            }
        }
        float4 b = *(const float4*)&b1[4 * cq];
        float4 ha, hb;
        ha.x = fmaxf(accA.x + b.x, 0.f); ha.y = fmaxf(accA.y + b.y, 0.f);
        ha.z = fmaxf(accA.z + b.z, 0.f); ha.w = fmaxf(accA.w + b.w, 0.f);
        hb.x = fmaxf(accB.x + b.x, 0.f); hb.y = fmaxf(accB.y + b.y, 0.f);
        hb.z = fmaxf(accB.z + b.z, 0.f); hb.w = fmaxf(accB.w + b.w, 0.f);
        *(float4*)&sH[(2 * rg) * HID + 4 * cq] = ha;
        *(float4*)&sH[(2 * rg + 1) * HID + 4 * cq] = hb;
    }
    {   // layer 2: thread = (1 col, 4 rows)
        int c = t & 127, half = t >> 7;
        float acc2[4] = {0.f, 0.f, 0.f, 0.f};
        for (int kt = 0; kt < HID / 32; ++kt) {
            __syncthreads();
#pragma unroll
            for (int i = 0; i < 4; ++i) {     // stage W2 tile [32][128]
                int idx = i * 256 + t;
                int kr = idx >> 5, q = idx & 31;
                sW4[kr * 32 + q] = *(const float4*)&W2[(size_t)(kt * 32 + kr) * OUT_DIM + 4 * q];
            }
            __syncthreads();
#pragma unroll
            for (int kk = 0; kk < 32; ++kk) {
                int k = kt * 32 + kk;
                float w = sW[kk * 128 + c];
#pragma unroll
                for (int r = 0; r < 4; ++r)
                    acc2[r] = fmaf(sH[(half * 4 + r) * HID + k], w, acc2[r]);
            }
        }
        float b = b2[c];
#pragma unroll
        for (int r = 0; r < 4; ++r) {
            int row = r0 + half * 4 + r;
            float v = acc2[r] + b;
            F0[(size_t)row * OUT_DIM + c] = v;
            X0[(size_t)row * OUT_DIM + c] = v * DsqInv[row];
        }
    }
}

// ---------------------------------------------------------------------------
// sq[i] = ||X_i||^2  (one wave per row)
__global__ void k_sq0(const float* __restrict__ X, float* __restrict__ sq) {
    int wid = threadIdx.x >> 6, lane = threadIdx.x & 63;
    int row = blockIdx.x * 4 + wid;
    float2 x = ((const float2*)X)[row * 64 + lane];
    float s = x.x * x.x + x.y * x.y;
#pragma unroll
    for (int m = 1; m < 64; m <<= 1) s += __shfl_xor(s, m);
    if (lane == 0) sq[row] = s;
}

// ---------------------------------------------------------------------------
// IRLS step v5: wave per row, 8-lane group per edge, COALESCED lane->dim map.
// Lane (g,oc) reads edge g's row at float4 indices {oc, 8+oc, 16+oc, 24+oc}:
// each load instruction covers 8 contiguous 128B lines (TCP minimum), vs 32
// partial lines with the old oc*16 layout.  Precomputed sq; LDS combine.
__global__ __launch_bounds__(256) void k_prop(const float* __restrict__ X,
                       const float* __restrict__ F0,
                       const unsigned short* __restrict__ cols, const int* __restrict__ deg,
                       const float* __restrict__ DsqInv, const float* __restrict__ Dinv,
                       const float* __restrict__ sq_in,
                       float* __restrict__ Xout, float* __restrict__ sq_out,
                       float* __restrict__ FcOut, int final_step) {
    __shared__ unsigned short sCols[4][MAXDEG];
    __shared__ __align__(16) float sPart[4][8][136];  // pad 136: 16B-aligned, <=2-way
    int t = threadIdx.x;
    int wid = t >> 6, lane = t & 63;
    int row = blockIdx.x * 4 + wid;
    int g = lane >> 3, oc = lane & 7;
    int dg = deg[row];
    for (int e = lane; e < dg; e += 64) sCols[wid][e] = cols[(size_t)row * MAXDEG + e];
    float sqi = sq_in[row];
    // X_i slice, coalesced map: lane covers dims {32i + 4*oc .. +3}, i=0..3
    const float4* Xr4 = (const float4*)(X + (size_t)row * 128);
    float4 xi0 = Xr4[oc], xi1 = Xr4[8 + oc], xi2 = Xr4[16 + oc], xi3 = Xr4[24 + oc];
    __syncthreads();
    float4 a0 = make_float4(0.f,0.f,0.f,0.f), a1 = make_float4(0.f,0.f,0.f,0.f);
    float4 a2 = make_float4(0.f,0.f,0.f,0.f), a3 = make_float4(0.f,0.f,0.f,0.f);
    float qacc = 0.f;
    int nch = (dg + 7) >> 3;
    for (int ch = 0; ch < nch; ++ch) {
        int e = ch * 8 + g;
        bool act = e < dg;
        int j = (int)sCols[wid][act ? e : 0];
        const float4* Xj4 = (const float4*)(X + (size_t)j * 128);
        float4 c0 = Xj4[oc], c1 = Xj4[8 + oc], c2 = Xj4[16 + oc], c3 = Xj4[24 + oc];
        float sqj = sq_in[j];
        float pA = 0.f, pB = 0.f;
        pA = fmaf(xi0.x, c0.x, pA); pB = fmaf(xi0.y, c0.y, pB);
        pA = fmaf(xi0.z, c0.z, pA); pB = fmaf(xi0.w, c0.w, pB);
        pA = fmaf(xi1.x, c1.x, pA); pB = fmaf(xi1.y, c1.y, pB);
        pA = fmaf(xi1.z, c1.z, pA); pB = fmaf(xi1.w, c1.w, pB);
        pA = fmaf(xi2.x, c2.x, pA); pB = fmaf(xi2.y, c2.y, pB);
        pA = fmaf(xi2.z, c2.z, pA); pB = fmaf(xi2.w, c2.w, pB);
        pA = fmaf(xi3.x, c3.x, pA); pB = fmaf(xi3.y, c3.y, pB);
        pA = fmaf(xi3.z, c3.z, pA); pB = fmaf(xi3.w, c3.w, pB);
        float p = pA + pB;
        p += __shfl_xor(p, 1);
        p += __shfl_xor(p, 2);
        p += __shfl_xor(p, 4);
        float z = fmaxf(sqi + sqj - 2.f * p, 0.f);
        float w = fmaxf(1.f - sqrtf(z) * INV_GAMMA, 0.f);
        w = act ? w : 0.f;
        qacc += w;
        a0.x = fmaf(w, c0.x, a0.x); a0.y = fmaf(w, c0.y, a0.y);
        a0.z = fmaf(w, c0.z, a0.z); a0.w = fmaf(w, c0.w, a0.w);
        a1.x = fmaf(w, c1.x, a1.x); a1.y = fmaf(w, c1.y, a1.y);
        a1.z = fmaf(w, c1.z, a1.z); a1.w = fmaf(w, c1.w, a1.w);
        a2.x = fmaf(w, c2.x, a2.x); a2.y = fmaf(w, c2.y, a2.y);
        a2.z = fmaf(w, c2.z, a2.z); a2.w = fmaf(w, c2.w, a2.w);
        a3.x = fmaf(w, c3.x, a3.x); a3.y = fmaf(w, c3.y, a3.y);
        a3.z = fmaf(w, c3.z, a3.z); a3.w = fmaf(w, c3.w, a3.w);
    }
    // write partials: slot g holds this group's 128-dim partial + qacc
    {
        float* part = &sPart[wid][g][0];
        *(float4*)&part[ 0 + 4 * oc] = a0;
        *(float4*)&part[32 + 4 * oc] = a1;
        *(float4*)&part[64 + 4 * oc] = a2;
        *(float4*)&part[96 + 4 * oc] = a3;
        if (oc == 0) part[128] = qacc;
    }
    __syncthreads();
    // combine: wave wid reduces its own row; lane handles dims 2*lane, 2*lane+1
    int d0 = lane * 2;
    float accX = 0.f, accY = 0.f, qs = 0.f;
#pragma unroll
    for (int s = 0; s < 8; ++s) {
        float2 v = *(const float2*)&sPart[wid][s][d0];
        accX += v.x; accY += v.y;
        qs += sPart[wid][s][128];
    }
    float dsi = DsqInv[row];
    float invQ = 1.f / (qs * Dinv[row] + LAM);
    float2 f0 = *(const float2*)&F0[(size_t)row * 128 + d0];
    float ox = (dsi * accX + LAM * f0.x) * invQ;
    float oy = (dsi * accY + LAM * f0.y) * invQ;
    if (final_step) {
        *(float2*)&FcOut[(size_t)row * 128 + d0] = make_float2(ox, oy);
    } else {
        float xx = ox * dsi, xy = oy * dsi;
        *(float2*)&Xout[(size_t)row * 128 + d0] = make_float2(xx, xy);
        float ss = xx * xx + xy * xy;
#pragma unroll
        for (int m = 1; m < 64; m <<= 1) ss += __shfl_xor(ss, m);
        if (lane == 0) sq_out[row] = ss;
    }
}

extern "C" void kernel_launch(void* const* d_in, const int* in_sizes, int n_in,
                              void* d_out, int out_size, void* d_ws, size_t ws_size,
                              hipStream_t stream) {
    const float *A = nullptr, *F = nullptr, *W1 = nullptr, *b1 = nullptr,
                *W2 = nullptr, *b2 = nullptr;
    for (int i = 0; i < n_in; i++) {
        switch (in_sizes[i]) {
            case NN * NN:        A  = (const float*)d_in[i]; break;
            case NN * IN_DIM:    F  = (const float*)d_in[i]; break;
            case IN_DIM * HID:   W1 = (const float*)d_in[i]; break;
            case HID:            b1 = (const float*)d_in[i]; break;
            case HID * OUT_DIM:  W2 = (const float*)d_in[i]; break;
            case OUT_DIM:        b2 = (const float*)d_in[i]; break;
            default: break;
        }
    }
    float* out = (float*)d_out;

    char* ws = (char*)d_ws;
    float* F0     = (float*)ws; ws += (size_t)NN * OUT_DIM * 4;   // 2 MB
    float* XA     = (float*)ws; ws += (size_t)NN * OUT_DIM * 4;   // 2 MB
    float* XB     = (float*)ws; ws += (size_t)NN * OUT_DIM * 4;   // 2 MB
    float* DsqInv = (float*)ws; ws += (size_t)NN * 4;
    float* Dinv   = (float*)ws; ws += (size_t)NN * 4;
    float* sqA    = (float*)ws; ws += (size_t)NN * 4;
    float* sqB    = (float*)ws; ws += (size_t)NN * 4;
    int*   deg    = (int*)ws;   ws += (size_t)NN * 4;
    unsigned short* cols = (unsigned short*)ws; ws += (size_t)NN * MAXDEG * 2; // 1.5 MB

    hipLaunchKernelGGL(k_analyze, dim3(NN / 4), dim3(256), 0, stream, A, cols, deg, DsqInv, Dinv);
    hipLaunchKernelGGL(k_mlp, dim3(NN / 8), dim3(256), 0, stream,
                       F, W1, b1, W2, b2, DsqInv, F0, XA);
    hipLaunchKernelGGL(k_sq0, dim3(NN / 4), dim3(256), 0, stream, XA, sqA);

    float* Xc = XA; float* Xn = XB;
    float* sqc = sqA; float* sqn = sqB;
    for (int step = 0; step < PROP_STEPS; step++) {
        int fin = (step == PROP_STEPS - 1) ? 1 : 0;
        hipLaunchKernelGGL(k_prop, dim3(NN / 4), dim3(256), 0, stream,
                           Xc, F0, cols, deg, DsqInv, Dinv, sqc, Xn, sqn, out, fin);
        float* t1 = Xc; Xc = Xn; Xn = t1;
        float* t2 = sqc; sqc = sqn; sqn = t2;
    }
}

// Round 11
// 259.062 us; speedup vs baseline: 1.3352x; 1.0189x over previous
//
#include <hip/hip_runtime.h>
#include <hip/hip_fp16.h>

#define NN 4096
#define IN_DIM 512
#define HID 256
#define OUT_DIM 128
#define MAXDEG 192
#define INV_GAMMA (1.0f / 6.0f)
#define LAM 0.11111111111111116f   // 1/0.9 - 1
#define PROP_STEPS 10

// ---------------------------------------------------------------------------
// Dense A scan (float4): per-row adjacency list, degree, D=rowsum+1, 1/D, 1/sqrt(D).
__global__ void k_analyze(const float* __restrict__ A, unsigned short* __restrict__ cols,
                          int* __restrict__ deg, float* __restrict__ DsqInv,
                          float* __restrict__ Dinv) {
    int wid = threadIdx.x >> 6, lane = threadIdx.x & 63;
    int row = blockIdx.x * 4 + wid;
    const float4* Ar = (const float4*)(A + (size_t)row * NN);
    unsigned short* crow = cols + (size_t)row * MAXDEG;
    int cnt = 0;
    float fsum = 0.f;
    for (int it = 0; it < NN / 256; ++it) {
        float4 v = Ar[it * 64 + lane];
        fsum += (v.x + v.y) + (v.z + v.w);
        int colbase = (it * 64 + lane) * 4;
        float comp[4] = {v.x, v.y, v.z, v.w};
#pragma unroll
        for (int c = 0; c < 4; ++c) {
            bool nz = (comp[c] != 0.f);
            unsigned long long m = __ballot(nz);
            if (nz) {
                int off = cnt + __popcll(m & ((1ull << lane) - 1ull));
                if (off < MAXDEG) crow[off] = (unsigned short)(colbase + c);
            }
            cnt += __popcll(m);
        }
    }
#pragma unroll
    for (int m = 1; m < 64; m <<= 1) fsum += __shfl_xor(fsum, m);
    if (lane == 0) {
        float D = fsum + 1.0f;
        deg[row] = cnt < MAXDEG ? cnt : MAXDEG;
        DsqInv[row] = 1.0f / sqrtf(D);
        Dinv[row] = 1.0f / D;
    }
}

// ---------------------------------------------------------------------------
// Fused MLP (round-8 structure; X0 now written as fp16).
__global__ __launch_bounds__(256) void k_mlp(const float* __restrict__ F,
                      const float* __restrict__ W1, const float* __restrict__ b1,
                      const float* __restrict__ W2, const float* __restrict__ b2,
                      const float* __restrict__ DsqInv,
                      float* __restrict__ F0, __half* __restrict__ Xh0) {
    __shared__ __align__(16) float sF[8 * IN_DIM];   // 16 KB
    __shared__ __align__(16) float sW[32 * 256];     // 32 KB
    __shared__ __align__(16) float sH[8 * HID];      // 8 KB
    int r0 = blockIdx.x * 8;
    int t = threadIdx.x;
    float4* sF4 = (float4*)sF;
    float4* sW4 = (float4*)sW;
#pragma unroll
    for (int i = 0; i < 4; ++i) {
        int idx = i * 256 + t;
        int r = idx >> 7, q = idx & 127;
        sF4[r * 128 + q] = *(const float4*)&F[(size_t)(r0 + r) * IN_DIM + 4 * q];
    }
    {   // layer 1: thread = (4 cols, 2 rows)
        int cq = t & 63, rg = t >> 6;
        float4 accA = make_float4(0.f, 0.f, 0.f, 0.f);
        float4 accB = make_float4(0.f, 0.f, 0.f, 0.f);
        for (int kt = 0; kt < IN_DIM / 32; ++kt) {
            __syncthreads();
#pragma unroll
            for (int i = 0; i < 8; ++i) {     // stage W1 tile [32][256]
                int idx = i * 256 + t;
                int kr = idx >> 6, q = idx & 63;
                sW4[kr * 64 + q] = *(const float4*)&W1[(size_t)(kt * 32 + kr) * HID + 4 * q];
            }
            __syncthreads();
#pragma unroll
            for (int g4 = 0; g4 < 8; ++g4) {
                float4 w0 = sW4[(4 * g4 + 0) * 64 + cq];
                float4 w1 = sW4[(4 * g4 + 1) * 64 + cq];
                float4 w2 = sW4[(4 * g4 + 2) * 64 + cq];
                float4 w3 = sW4[(4 * g4 + 3) * 64 + cq];
                float4 fA = sF4[(2 * rg) * 128 + kt * 8 + g4];
                float4 fB = sF4[(2 * rg + 1) * 128 + kt * 8 + g4];
                accA.x = fmaf(fA.x, w0.x, accA.x); accA.y = fmaf(fA.x, w0.y, accA.y);
                accA.z = fmaf(fA.x, w0.z, accA.z); accA.w = fmaf(fA.x, w0.w, accA.w);
                accA.x = fmaf(fA.y, w1.x, accA.x); accA.y = fmaf(fA.y, w1.y, accA.y);
                accA.z = fmaf(fA.y, w1.z, accA.z); accA.w = fmaf(fA.y, w1.w, accA.w);
                accA.x = fmaf(fA.z, w2.x, accA.x); accA.y = fmaf(fA.z, w2.y, accA.y);
                accA.z = fmaf(fA.z, w2.z, accA.z); accA.w = fmaf(fA.z, w2.w, accA.w);
                accA.x = fmaf(fA.w, w3.x, accA.x); accA.y = fmaf(fA.w, w3.y, accA.y);
                accA.z = fmaf(fA.w, w3.z, accA.z); accA.w = fmaf(fA.w, w3.w, accA.w);
                accB.x = fmaf(fB.x, w0.x, accB.x); accB.y = fmaf(fB.x, w0.y, accB.y);
                accB.z = fmaf(fB.x, w0.z, accB.z); accB.w = fmaf(fB.x, w0.w, accB.w);
                accB.x = fmaf(fB.y, w1.x, accB.x); accB.y = fmaf(fB.y, w1.y, accB.y);
                accB.z = fmaf(fB.y, w1.z, accB.z); accB.w = fmaf(fB.y, w1.w, accB.w);
                accB.x = fmaf(fB.z, w2.x, accB.x); accB.y = fmaf(fB.z, w2.y, accB.y);
                accB.z = fmaf(fB.z, w2.z, accB.z); accB.w = fmaf(fB.z, w2.w, accB.w);
                accB.x = fmaf(fB.w, w3.x, accB.x); accB.y = fmaf(fB.w, w3.y, accB.y);
                accB.z = fmaf(fB.w, w3.z, accB.z); accB.w = fmaf(fB.w, w3.w, accB.w);
            }
        }
        float4 b = *(const float4*)&b1[4 * cq];
        float4 ha, hb;
        ha.x = fmaxf(accA.x + b.x, 0.f); ha.y = fmaxf(accA.y + b.y, 0.f);
        ha.z = fmaxf(accA.z + b.z, 0.f); ha.w = fmaxf(accA.w + b.w, 0.f);
        hb.x = fmaxf(accB.x + b.x, 0.f); hb.y = fmaxf(accB.y + b.y, 0.f);
        hb.z = fmaxf(accB.z + b.z, 0.f); hb.w = fmaxf(accB.w + b.w, 0.f);
        *(float4*)&sH[(2 * rg) * HID + 4 * cq] = ha;
        *(float4*)&sH[(2 * rg + 1) * HID + 4 * cq] = hb;
    }
    {   // layer 2: thread = (1 col, 4 rows)
        int c = t & 127, half = t >> 7;
        float acc2[4] = {0.f, 0.f, 0.f, 0.f};
        for (int kt = 0; kt < HID / 32; ++kt) {
            __syncthreads();
#pragma unroll
            for (int i = 0; i < 4; ++i) {     // stage W2 tile [32][128]
                int idx = i * 256 + t;
                int kr = idx >> 5, q = idx & 31;
                sW4[kr * 32 + q] = *(const float4*)&W2[(size_t)(kt * 32 + kr) * OUT_DIM + 4 * q];
            }
            __syncthreads();
#pragma unroll
            for (int kk = 0; kk < 32; ++kk) {
                int k = kt * 32 + kk;
                float w = sW[kk * 128 + c];
#pragma unroll
                for (int r = 0; r < 4; ++r)
                    acc2[r] = fmaf(sH[(half * 4 + r) * HID + k], w, acc2[r]);
            }
        }
        float b = b2[c];
#pragma unroll
        for (int r = 0; r < 4; ++r) {
            int row = r0 + half * 4 + r;
            float v = acc2[r] + b;
            F0[(size_t)row * OUT_DIM + c] = v;
            Xh0[(size_t)row * OUT_DIM + c] = __float2half(v * DsqInv[row]);
        }
    }
}

// ---------------------------------------------------------------------------
// sq[i] = ||X_i||^2 computed from the fp16-rounded X (consistency with gather).
__global__ void k_sq0(const __half* __restrict__ Xh, float* __restrict__ sq) {
    int wid = threadIdx.x >> 6, lane = threadIdx.x & 63;
    int row = blockIdx.x * 4 + wid;
    float2 x = __half22float2(((const __half2*)Xh)[row * 64 + lane]);
    float s = x.x * x.x + x.y * x.y;
#pragma unroll
    for (int m = 1; m < 64; m <<= 1) s += __shfl_xor(s, m);
    if (lane == 0) sq[row] = s;
}

// ---------------------------------------------------------------------------
// IRLS step v6: wave per row, 8-lane group per edge, X stored fp16 (256B/row,
// 2 coalesced 128B-line loads per edge vs 4).  Distances/weights from fp16;
// IRLS update (F0, Q, output) in fp32.  Precomputed sq; LDS partial combine.
__global__ __launch_bounds__(256) void k_prop(const __half* __restrict__ Xh,
                       const float* __restrict__ F0,
                       const unsigned short* __restrict__ cols, const int* __restrict__ deg,
                       const float* __restrict__ DsqInv, const float* __restrict__ Dinv,
                       const float* __restrict__ sq_in,
                       __half* __restrict__ Xhout, float* __restrict__ sq_out,
                       float* __restrict__ FcOut, int final_step) {
    __shared__ unsigned short sCols[4][MAXDEG];
    __shared__ __align__(16) float sPart[4][8][136];  // pad 136: 16B-aligned
    union F4H { float4 f4; __half2 h2[4]; };
    int t = threadIdx.x;
    int wid = t >> 6, lane = t & 63;
    int row = blockIdx.x * 4 + wid;
    int g = lane >> 3, oc = lane & 7;
    int dg = deg[row];
    for (int e = lane; e < dg; e += 64) sCols[wid][e] = cols[(size_t)row * MAXDEG + e];
    float sqi = sq_in[row];
    // X_i slice: lane covers dims [8oc..8oc+8) and [64+8oc..64+8oc+8)
    const float4* Xi4 = (const float4*)(Xh + (size_t)row * 128);
    float xi[16];
    {
        F4H u0, u1;
        u0.f4 = Xi4[oc];
        u1.f4 = Xi4[8 + oc];
#pragma unroll
        for (int k = 0; k < 4; ++k) {
            float2 f = __half22float2(u0.h2[k]);
            xi[2 * k] = f.x; xi[2 * k + 1] = f.y;
        }
#pragma unroll
        for (int k = 0; k < 4; ++k) {
            float2 f = __half22float2(u1.h2[k]);
            xi[8 + 2 * k] = f.x; xi[8 + 2 * k + 1] = f.y;
        }
    }
    __syncthreads();
    float acc[16];
#pragma unroll
    for (int k = 0; k < 16; ++k) acc[k] = 0.f;
    float qacc = 0.f;
    int nch = (dg + 7) >> 3;
    for (int ch = 0; ch < nch; ++ch) {
        int e = ch * 8 + g;
        bool act = e < dg;
        int j = (int)sCols[wid][act ? e : 0];
        const float4* Xj4 = (const float4*)(Xh + (size_t)j * 128);
        F4H u0, u1;
        u0.f4 = Xj4[oc];
        u1.f4 = Xj4[8 + oc];
        float sqj = sq_in[j];
        float cj[16];
#pragma unroll
        for (int k = 0; k < 4; ++k) {
            float2 f = __half22float2(u0.h2[k]);
            cj[2 * k] = f.x; cj[2 * k + 1] = f.y;
        }
#pragma unroll
        for (int k = 0; k < 4; ++k) {
            float2 f = __half22float2(u1.h2[k]);
            cj[8 + 2 * k] = f.x; cj[8 + 2 * k + 1] = f.y;
        }
        float pA = 0.f, pB = 0.f;
#pragma unroll
        for (int k = 0; k < 8; ++k) {
            pA = fmaf(xi[k], cj[k], pA);
            pB = fmaf(xi[8 + k], cj[8 + k], pB);
        }
        float p = pA + pB;
        p += __shfl_xor(p, 1);
        p += __shfl_xor(p, 2);
        p += __shfl_xor(p, 4);
        float z = fmaxf(sqi + sqj - 2.f * p, 0.f);
        float w = fmaxf(1.f - sqrtf(z) * INV_GAMMA, 0.f);
        w = act ? w : 0.f;
        qacc += w;
#pragma unroll
        for (int k = 0; k < 16; ++k) acc[k] = fmaf(w, cj[k], acc[k]);
    }
    // write partials: slot g holds this group's 128-dim partial + qacc
    {
        float* part = &sPart[wid][g][0];
        *(float4*)&part[8 * oc]      = make_float4(acc[0], acc[1], acc[2], acc[3]);
        *(float4*)&part[8 * oc + 4]  = make_float4(acc[4], acc[5], acc[6], acc[7]);
        *(float4*)&part[64 + 8 * oc]     = make_float4(acc[8], acc[9], acc[10], acc[11]);
        *(float4*)&part[64 + 8 * oc + 4] = make_float4(acc[12], acc[13], acc[14], acc[15]);
        if (oc == 0) part[128] = qacc;
    }
    __syncthreads();
    // combine: wave wid reduces its own row; lane handles dims 2*lane, 2*lane+1
    int d0 = lane * 2;
    float accX = 0.f, accY = 0.f, qs = 0.f;
#pragma unroll
    for (int s = 0; s < 8; ++s) {
        float2 v = *(const float2*)&sPart[wid][s][d0];
        accX += v.x; accY += v.y;
        qs += sPart[wid][s][128];
    }
    float dsi = DsqInv[row];
    float invQ = 1.f / (qs * Dinv[row] + LAM);
    float2 f0 = *(const float2*)&F0[(size_t)row * 128 + d0];
    float ox = (dsi * accX + LAM * f0.x) * invQ;
    float oy = (dsi * accY + LAM * f0.y) * invQ;
    if (final_step) {
        *(float2*)&FcOut[(size_t)row * 128 + d0] = make_float2(ox, oy);
    } else {
        float xx = ox * dsi, xy = oy * dsi;
        __half2 hx = __floats2half2_rn(xx, xy);
        ((__half2*)(Xhout + (size_t)row * 128))[lane] = hx;
        float2 xr = __half22float2(hx);   // sq from the rounded values
        float ss = xr.x * xr.x + xr.y * xr.y;
#pragma unroll
        for (int m = 1; m < 64; m <<= 1) ss += __shfl_xor(ss, m);
        if (lane == 0) sq_out[row] = ss;
    }
}

extern "C" void kernel_launch(void* const* d_in, const int* in_sizes, int n_in,
                              void* d_out, int out_size, void* d_ws, size_t ws_size,
                              hipStream_t stream) {
    const float *A = nullptr, *F = nullptr, *W1 = nullptr, *b1 = nullptr,
                *W2 = nullptr, *b2 = nullptr;
    for (int i = 0; i < n_in; i++) {
        switch (in_sizes[i]) {
            case NN * NN:        A  = (const float*)d_in[i]; break;
            case NN * IN_DIM:    F  = (const float*)d_in[i]; break;
            case IN_DIM * HID:   W1 = (const float*)d_in[i]; break;
            case HID:            b1 = (const float*)d_in[i]; break;
            case HID * OUT_DIM:  W2 = (const float*)d_in[i]; break;
            case OUT_DIM:        b2 = (const float*)d_in[i]; break;
            default: break;
        }
    }
    float* out = (float*)d_out;

    char* ws = (char*)d_ws;
    float* F0      = (float*)ws;  ws += (size_t)NN * OUT_DIM * 4;   // 2 MB
    __half* XhA    = (__half*)ws; ws += (size_t)NN * OUT_DIM * 2;   // 1 MB
    __half* XhB    = (__half*)ws; ws += (size_t)NN * OUT_DIM * 2;   // 1 MB
    float* DsqInv  = (float*)ws;  ws += (size_t)NN * 4;
    float* Dinv    = (float*)ws;  ws += (size_t)NN * 4;
    float* sqA     = (float*)ws;  ws += (size_t)NN * 4;
    float* sqB     = (float*)ws;  ws += (size_t)NN * 4;
    int*   deg     = (int*)ws;    ws += (size_t)NN * 4;
    unsigned short* cols = (unsigned short*)ws; ws += (size_t)NN * MAXDEG * 2; // 1.5 MB

    hipLaunchKernelGGL(k_analyze, dim3(NN / 4), dim3(256), 0, stream, A, cols, deg, DsqInv, Dinv);
    hipLaunchKernelGGL(k_mlp, dim3(NN / 8), dim3(256), 0, stream,
                       F, W1, b1, W2, b2, DsqInv, F0, XhA);
    hipLaunchKernelGGL(k_sq0, dim3(NN / 4), dim3(256), 0, stream, XhA, sqA);

    __half* Xc = XhA; __half* Xn = XhB;
    float* sqc = sqA; float* sqn = sqB;
    for (int step = 0; step < PROP_STEPS; step++) {
        int fin = (step == PROP_STEPS - 1) ? 1 : 0;
        hipLaunchKernelGGL(k_prop, dim3(NN / 4), dim3(256), 0, stream,
                           Xc, F0, cols, deg, DsqInv, Dinv, sqc, Xn, sqn, out, fin);
        __half* t1 = Xc; Xc = Xn; Xn = t1;
        float* t2 = sqc; sqc = sqn; sqn = t2;
    }
}